// Round 8
// baseline (106.998 us; speedup 1.0000x reference)
//
#include <hip/hip_runtime.h>
#include <hip/hip_bf16.h>

#define DIN  136
#define HH   128
#define NSEQ 256
#define NB   256
#define ST   136          // LDS row stride (elements); 272 B, 16B-aligned rows

typedef __attribute__((ext_vector_type(4)))  float f32x4;
typedef __attribute__((ext_vector_type(16))) float f32x16;
typedef __attribute__((ext_vector_type(8)))  short bf16x8;

static __device__ __forceinline__ unsigned cvt2(float lo, float hi) {
    __hip_bfloat162 h = __float22bfloat162_rn(make_float2(lo, hi));
    return *(unsigned*)&h;
}
static __device__ __forceinline__ short f2bf1(float f) {
    __hip_bfloat16 h = __float2bfloat16(f);
    return *(short*)&h;
}

// ---------------------------------------------------------------------------
// Prep: weights in LDS-final layout. w1s[n][k]=bf16(W1[k][n]) [128][136];
// w2s[n][k]=bf16(W2[k][n]) (k<128, else 0) [128][136]; contiguous for the
// fused kernel's single linear 69.6 KB copy.
// ---------------------------------------------------------------------------
__global__ __launch_bounds__(256)
void prep_kernel(const float* __restrict__ W1, const float* __restrict__ W2,
                 short* __restrict__ w1s, short* __restrict__ w2s)
{
    const int nt = gridDim.x * 256;
    const int idx = blockIdx.x * 256 + threadIdx.x;
    for (int e = idx; e < HH * ST; e += nt) {
        const int n = e / ST, k = e - n * ST;
        w1s[e] = f2bf1(W1[k * HH + n]);
    }
    for (int e = idx; e < HH * ST; e += nt) {
        const int n = e / ST, k = e - n * ST;
        w2s[e] = (k < HH) ? f2bf1(W2[k * HH + n]) : (short)0;
    }
}

// ---------------------------------------------------------------------------
// Fused kernel v4: one block = one query, 1024 threads (16 waves).
// Staging: BURST — all global loads issued back-to-back into registers
// (1 memory round trip), then convert/store to LDS.
// MLP: waves 0-7 only, 32 rows each, mfma_f32_32x32x16_bf16 (halves per-CU
// LDS weight re-read traffic vs 16 waves x 16x16x32). K-tail (136=8*16+8)
// via kg==0-masked step. h1 transposed into the wave's OWN feature rows
// (same-wave DS ordering -> no inter-layer barrier).
// Lambda: all 16 waves, as round 7.
// ---------------------------------------------------------------------------
__global__ __launch_bounds__(1024, 4)
void fused_kernel(const float* __restrict__ features,
                  const int*   __restrict__ labels,
                  const short* __restrict__ w1s,   // [128][136] bf16
                  const short* __restrict__ w2s,   // [128][136] bf16
                  const float* __restrict__ b1, const float* __restrict__ b2,
                  const float* __restrict__ W3, const float* __restrict__ b3,
                  float* __restrict__ out)
{
    __shared__ __align__(16) char smem[139264];
    short* a_lds  = (short*)smem;                  // [256][136] features -> h1
    short* w1_lds = (short*)(smem + 69632);        // [128][136]
    short* w2_lds = (short*)(smem + 104448);       // [128][136]
    float4* sp    = (float4*)smem;                 // overlay (post layer-2)
    float (*s_part)[NSEQ] = (float (*)[NSEQ])(smem + 4096);

    const int t    = threadIdx.x;
    const int lane = t & 63;
    const int wv   = t >> 6;
    const long row0 = (long)blockIdx.x * NSEQ;     // query = blockIdx.x

    // ================= burst staging: issue ALL loads first =================
    const f32x4* fsrc = (const f32x4*)(features + row0 * DIN);   // 8704 f32x4
    f32x4 fg[8];
#pragma unroll
    for (int m = 0; m < 8; ++m) fg[m] = fsrc[t + m * 1024];
    f32x4 fg8 = {};
    if (t < 512) fg8 = fsrc[8192 + t];

    const uint4* wsrc = (const uint4*)w1s;                       // 4352 uint4
    uint4 wg[4];
#pragma unroll
    for (int m = 0; m < 4; ++m) wg[m] = wsrc[t + m * 1024];
    uint4 wg4 = {};
    if (t < 256) wg4 = wsrc[4096 + t];

    // ---- convert + store features (34 f32x4 per row, exact) ----
#pragma unroll
    for (int m = 0; m < 8; ++m) {
        const int i = t + m * 1024;
        const int r = i / 34, c = i - r * 34;
        uint2 p; p.x = cvt2(fg[m].x, fg[m].y); p.y = cvt2(fg[m].z, fg[m].w);
        *(uint2*)&a_lds[r * ST + c * 4] = p;
    }
    if (t < 512) {
        const int i = 8192 + t;
        const int r = i / 34, c = i - r * 34;
        uint2 p; p.x = cvt2(fg8.x, fg8.y); p.y = cvt2(fg8.z, fg8.w);
        *(uint2*)&a_lds[r * ST + c * 4] = p;
    }
    // ---- store weights (linear) ----
    {
        uint4* wdst = (uint4*)w1_lds;
#pragma unroll
        for (int m = 0; m < 4; ++m) wdst[t + m * 1024] = wg[m];
        if (t < 256) wdst[4096 + t] = wg4;
    }
    __syncthreads();

    // ======================= MLP: waves 0-7, 32 rows each ===================
    f32x16 acc2[4];                    // layer-2 accum, used again in layer 3
    const int l31 = lane & 31;
    const int kg  = lane >> 5;
    if (t < 512) {
        const int mw   = wv;                       // 0..7
        const int arow = (mw * 32 + l31) * ST;

        // ---- layer 1: h1 = relu(A @ W1 + b1), K = 8*16 + 8 ----
        f32x16 acc[4];
#pragma unroll
        for (int tn = 0; tn < 4; ++tn) {
            const float bv = b1[tn * 32 + l31];
#pragma unroll
            for (int q = 0; q < 16; ++q) acc[tn][q] = bv;
        }
        for (int kc = 0; kc < 8; ++kc) {
            const int kb = kc * 16 + kg * 8;
            const bf16x8 afr = *(const bf16x8*)&a_lds[arow + kb];
            bf16x8 bfr[4];
#pragma unroll
            for (int tn = 0; tn < 4; ++tn)
                bfr[tn] = *(const bf16x8*)&w1_lds[(tn * 32 + l31) * ST + kb];
#pragma unroll
            for (int tn = 0; tn < 4; ++tn)
                acc[tn] = __builtin_amdgcn_mfma_f32_32x32x16_bf16(afr, bfr[tn], acc[tn], 0, 0, 0);
        }
        {   // K-tail 128..136: only kg==0 contributes, others feed zeros
            bf16x8 afr = (bf16x8){0,0,0,0,0,0,0,0};
            bf16x8 bfr[4];
#pragma unroll
            for (int tn = 0; tn < 4; ++tn) bfr[tn] = (bf16x8){0,0,0,0,0,0,0,0};
            if (kg == 0) {
                afr = *(const bf16x8*)&a_lds[arow + 128];
#pragma unroll
                for (int tn = 0; tn < 4; ++tn)
                    bfr[tn] = *(const bf16x8*)&w1_lds[(tn * 32 + l31) * ST + 128];
            }
#pragma unroll
            for (int tn = 0; tn < 4; ++tn)
                acc[tn] = __builtin_amdgcn_mfma_f32_32x32x16_bf16(afr, bfr[tn], acc[tn], 0, 0, 0);
        }

        // ---- relu(h1) -> bf16 into the wave's OWN rows (no barrier).
        //      C/D: col = l31, row = (q&3) + 8*(q>>2) + 4*kg  [m74/m101] ----
#pragma unroll
        for (int tn = 0; tn < 4; ++tn) {
            const int n = tn * 32 + l31;
#pragma unroll
            for (int q = 0; q < 16; ++q) {
                const int R = mw * 32 + (q & 3) + 8 * (q >> 2) + 4 * kg;
                a_lds[R * ST + n] = f2bf1(fmaxf(acc[tn][q], 0.f));
            }
        }

        // ---- layer 2: h2 = relu(h1 @ W2 + b2), K = 128 ----
#pragma unroll
        for (int tn = 0; tn < 4; ++tn) {
            const float bv = b2[tn * 32 + l31];
#pragma unroll
            for (int q = 0; q < 16; ++q) acc2[tn][q] = bv;
        }
        for (int kc = 0; kc < 8; ++kc) {
            const int kb = kc * 16 + kg * 8;
            const bf16x8 afr = *(const bf16x8*)&a_lds[arow + kb];
            bf16x8 bfr[4];
#pragma unroll
            for (int tn = 0; tn < 4; ++tn)
                bfr[tn] = *(const bf16x8*)&w2_lds[(tn * 32 + l31) * ST + kb];
#pragma unroll
            for (int tn = 0; tn < 4; ++tn)
                acc2[tn] = __builtin_amdgcn_mfma_f32_32x32x16_bf16(afr, bfr[tn], acc2[tn], 0, 0, 0);
        }
    }
    __syncthreads();   // all LDS reads done -> sp/s_part overlay is safe

    // ---- layer 3 + per-row pack {s*log2e, 0.5*gain, disc} into sp ----
    if (t < 512) {
        const int mw = wv;
        float w3v[4];
#pragma unroll
        for (int tn = 0; tn < 4; ++tn) w3v[tn] = W3[tn * 32 + l31];
        const float b3v = b3[0];
#pragma unroll
        for (int q = 0; q < 16; ++q) {
            float p = 0.f;
#pragma unroll
            for (int tn = 0; tn < 4; ++tn)
                p += fmaxf(acc2[tn][q], 0.f) * w3v[tn];
            p += __shfl_xor(p, 1, 64);
            p += __shfl_xor(p, 2, 64);
            p += __shfl_xor(p, 4, 64);
            p += __shfl_xor(p, 8, 64);
            p += __shfl_xor(p, 16, 64);
            if (l31 == 0) {
                const int row = mw * 32 + (q & 3) + 8 * (q >> 2) + 4 * kg;
                const float s = p + b3v;
                const int lab = labels[row0 + row];
                const float g = 0.5f * exp2f((float)lab);      // 0.5 folded
                const float disc = 1.f / (1.f + log2f(1.f + s));
                sp[row] = make_float4(s * 1.44269504088896f,   // log2e folded
                                      g, disc, 0.f);
            }
        }
    }
    __syncthreads();

    // ---- pairwise lambdas: i = t&255, jg = t>>8 (64 j each) ----
    {
        const int i  = t & (NSEQ - 1);
        const int jg = t >> 8;
        const float4 me = sp[i];
        const float sci = me.x, gi = me.y, di = me.z;
        float accum = 0.f;
        const int j0 = jg * 64;
#pragma unroll 8
        for (int jj = 0; jj < 64; ++jj) {
            const float4 o = sp[j0 + jj];
            const float dg = o.y - gi;                         // (gj-gi)/2
            const float e  = exp2f(o.x - sci);                 // exp(sj-si)
            const float r  = __builtin_amdgcn_rcpf(1.f + e);   // sigmoid(si-sj)
            const float dmax = (sci > o.x) ? di : o.z;         // disc of max
            const float dn = fabsf(dg) * dmax;                 // 0 when li==lj
            const float w  = (dg < 0.f) ? r : (r - 1.f);
            accum += dn * w;
        }
        s_part[jg][i] = accum;
    }
    __syncthreads();
    {
        const int i = t & (NSEQ - 1);
        if ((t >> 8) == 0)
            out[row0 + i] = s_part[0][i] + s_part[1][i] +
                            s_part[2][i] + s_part[3][i];
    }
}

// ---------------------------------------------------------------------------
extern "C" void kernel_launch(void* const* d_in, const int* in_sizes, int n_in,
                              void* d_out, int out_size, void* d_ws, size_t ws_size,
                              hipStream_t stream)
{
    const float* features = (const float*)d_in[0];
    const int*   labels   = (const int*)d_in[1];
    const float* W1 = (const float*)d_in[2];
    const float* b1 = (const float*)d_in[3];
    const float* W2 = (const float*)d_in[4];
    const float* b2 = (const float*)d_in[5];
    const float* W3 = (const float*)d_in[6];
    const float* b3 = (const float*)d_in[7];

    short* w1s = (short*)d_ws;             // [128][136] bf16
    short* w2s = w1s + HH * ST;            // [128][136] bf16 (contiguous)
    float* out = (float*)d_out;

    prep_kernel<<<64, 256, 0, stream>>>(W1, W2, w1s, w2s);
    fused_kernel<<<NB, 1024, 0, stream>>>(
        features, labels, w1s, w2s, b1, b2, W3, b3, out);
}